// Round 1
// baseline (8289.863 us; speedup 1.0000x reference)
//
#include <hip/hip_runtime.h>
#include <cmath>

#define N_LAYERS 24
#define D_MODEL 768
#define D_INNER 1536
#define D_STATE 16
#define DT_RANK 48
#define CONV_K 4
#define VOCAB 50280
#define SEQ 8
#define BATCH 64
#define NTOK (BATCH*SEQ)     /* 512 */
#define EPS 1e-5f
#define XZ_LD (2*D_INNER)    /* 3072 */
#define PROJ_LD (DT_RANK + 2*D_STATE) /* 80 */

// ---------------- embedding gather ----------------
__global__ void embed_gather(const int* __restrict__ ids, const float* __restrict__ embed,
                             float* __restrict__ h) {
    int row = blockIdx.x;                 // token 0..511
    int b = row / SEQ, t = row % SEQ;
    int id = ids[b * 64 + t];             // full_ids is (64,64), take [:, :SEQ]
    const float4* src = (const float4*)(embed + (size_t)id * D_MODEL);
    float4* dst = (float4*)(h + (size_t)row * D_MODEL);
    dst[threadIdx.x] = src[threadIdx.x];  // 192 threads * 4 = 768
}

// ---------------- rmsnorm ----------------
__global__ void rmsnorm_k(const float* __restrict__ x, const float* __restrict__ w,
                          float* __restrict__ out, int D) {
    int row = blockIdx.x;
    const float* xr = x + (size_t)row * D;
    float s = 0.f;
    for (int i = threadIdx.x; i < D; i += blockDim.x) { float v = xr[i]; s += v * v; }
    #pragma unroll
    for (int off = 32; off; off >>= 1) s += __shfl_down(s, off);
    __shared__ float red[8];
    int lane = threadIdx.x & 63, wid = threadIdx.x >> 6;
    if (lane == 0) red[wid] = s;
    __syncthreads();
    if (threadIdx.x == 0) {
        float tot = 0.f;
        for (int i = 0; i < (int)(blockDim.x >> 6); i++) tot += red[i];
        red[0] = rsqrtf(tot / (float)D + EPS);
    }
    __syncthreads();
    float r = red[0];
    for (int i = threadIdx.x; i < D; i += blockDim.x)
        out[(size_t)row * D + i] = xr[i] * r * w[i];
}

// ---------------- tiled fp32 GEMM: C[M,N] = A[M,K] @ B[N,K]^T (+ epilogue) ----------------
// epi: 0 = plain, 1 = softplus(acc + bias[n]), 2 = res[m,n] + acc (residual add)
// Requires M%64==0, K%16==0; N guarded. lda/ldb must be multiples of 4 (float4 loads).
#define BM 64
#define BN 64
#define BK 16
__global__ __launch_bounds__(256) void gemm_bt(
    const float* __restrict__ A, int lda,
    const float* __restrict__ B, int ldb,
    float* __restrict__ C, int ldc,
    int M, int N, int K,
    int epi, const float* __restrict__ bias, const float* __restrict__ res)
{
    __shared__ float As[BK][BM + 4];
    __shared__ float Bs[BK][BN + 4];
    int tid = threadIdx.x;
    int m0 = blockIdx.y * BM;
    int n0 = blockIdx.x * BN;
    int tx = tid & 15, ty = tid >> 4;
    int lr = tid >> 2;          // 0..63 (row within tile)
    int lk = (tid & 3) * 4;     // k-quad within BK
    float acc[4][4] = {};
    for (int k0 = 0; k0 < K; k0 += BK) {
        float4 av = *(const float4*)(A + (size_t)(m0 + lr) * lda + k0 + lk);
        As[lk + 0][lr] = av.x; As[lk + 1][lr] = av.y;
        As[lk + 2][lr] = av.z; As[lk + 3][lr] = av.w;
        int bn = n0 + lr;
        float4 bv = make_float4(0.f, 0.f, 0.f, 0.f);
        if (bn < N) bv = *(const float4*)(B + (size_t)bn * ldb + k0 + lk);
        Bs[lk + 0][lr] = bv.x; Bs[lk + 1][lr] = bv.y;
        Bs[lk + 2][lr] = bv.z; Bs[lk + 3][lr] = bv.w;
        __syncthreads();
        #pragma unroll
        for (int k = 0; k < BK; k++) {
            float a[4], b[4];
            #pragma unroll
            for (int i = 0; i < 4; i++) a[i] = As[k][ty * 4 + i];
            #pragma unroll
            for (int j = 0; j < 4; j++) b[j] = Bs[k][tx * 4 + j];
            #pragma unroll
            for (int i = 0; i < 4; i++)
                #pragma unroll
                for (int j = 0; j < 4; j++) acc[i][j] += a[i] * b[j];
        }
        __syncthreads();
    }
    #pragma unroll
    for (int i = 0; i < 4; i++) {
        int m = m0 + ty * 4 + i;
        #pragma unroll
        for (int j = 0; j < 4; j++) {
            int n = n0 + tx * 4 + j;
            if (n < N) {
                float v = acc[i][j];
                if (epi == 1) {
                    v += bias[n];
                    float sp = log1pf(expf(v));
                    v = (v > 20.f) ? v : sp;
                } else if (epi == 2) {
                    v += res[(size_t)m * ldc + n];
                }
                C[(size_t)m * ldc + n] = v;
            }
        }
    }
}

// ---------------- causal depthwise conv + bias + silu + mask ----------------
__global__ void conv_silu(const float* __restrict__ xz, const int* __restrict__ mask,
                          const float* __restrict__ cw, const float* __restrict__ cb,
                          float* __restrict__ xo)
{
    int idx = blockIdx.x * blockDim.x + threadIdx.x;
    if (idx >= NTOK * D_INNER) return;
    int d = idx % D_INNER;
    int row = idx / D_INNER;        // b*SEQ + t
    int t = row % SEQ, b = row / SEQ;
    float acc = cb[d];
    #pragma unroll
    for (int k = 0; k < CONV_K; k++) {
        int tt = t - (CONV_K - 1) + k;
        if (tt >= 0) {
            float xv = xz[(size_t)(b * SEQ + tt) * XZ_LD + d];
            float mf = (float)mask[b * 64 + tt];
            acc += xv * mf * cw[d * CONV_K + k];
        }
    }
    float mf = (float)mask[b * 64 + t];
    float sv = acc / (1.f + expf(-acc));   // silu
    xo[(size_t)row * D_INNER + d] = sv * mf;
}

// ---------------- selective scan + D-skip + z-gate ----------------
__global__ void scan_k(const float* __restrict__ xz, const float* __restrict__ xc,
                       const float* __restrict__ proj, const float* __restrict__ dt,
                       const float* __restrict__ A_log, const float* __restrict__ Dp,
                       float* __restrict__ y)
{
    int idx = blockIdx.x * blockDim.x + threadIdx.x;
    if (idx >= BATCH * D_INNER) return;
    int d = idx % D_INNER;
    int b = idx / D_INNER;
    float A[D_STATE];
    #pragma unroll
    for (int n = 0; n < D_STATE; n++) A[n] = -expf(A_log[d * D_STATE + n]);
    float Dv = Dp[d];
    float h[D_STATE];
    #pragma unroll
    for (int n = 0; n < D_STATE; n++) h[n] = 0.f;
    for (int t = 0; t < SEQ; t++) {
        int row = b * SEQ + t;
        float dtv = dt[(size_t)row * D_INNER + d];
        float xv = xc[(size_t)row * D_INNER + d];
        float yv = 0.f;
        #pragma unroll
        for (int n = 0; n < D_STATE; n++) {
            float dA = expf(dtv * A[n]);
            float Bv = proj[(size_t)row * PROJ_LD + DT_RANK + n];
            float Cv = proj[(size_t)row * PROJ_LD + DT_RANK + D_STATE + n];
            h[n] = dA * h[n] + dtv * Bv * xv;
            yv += h[n] * Cv;
        }
        yv += xv * Dv;
        float z = xz[(size_t)row * XZ_LD + D_INNER + d];
        yv *= z / (1.f + expf(-z));
        y[(size_t)row * D_INNER + d] = yv;
    }
}

extern "C" void kernel_launch(void* const* d_in, const int* in_sizes, int n_in,
                              void* d_out, int out_size, void* d_ws, size_t ws_size,
                              hipStream_t stream) {
    const int*   full_ids = (const int*)  d_in[0];
    const int*   full_mask= (const int*)  d_in[1];
    const float* embed    = (const float*)d_in[3];
    const float* norm_w   = (const float*)d_in[4];
    const float* in_w     = (const float*)d_in[5];
    const float* conv_w   = (const float*)d_in[6];
    const float* conv_b   = (const float*)d_in[7];
    const float* xp_w     = (const float*)d_in[8];
    const float* dtp_w    = (const float*)d_in[9];
    const float* dtp_b    = (const float*)d_in[10];
    const float* A_log    = (const float*)d_in[11];
    const float* Dp       = (const float*)d_in[12];
    const float* out_w    = (const float*)d_in[13];
    const float* norm_f_w = (const float*)d_in[14];
    float* out = (float*)d_out;

    // workspace carve-up (floats, 256B-aligned chunks)
    char* ws = (char*)d_ws;
    size_t off = 0;
    auto alloc = [&](size_t nfloats) {
        float* p = (float*)(ws + off);
        off += ((nfloats * 4 + 255) / 256) * 256;
        return p;
    };
    float* h    = alloc((size_t)NTOK * D_MODEL);
    float* hn   = alloc((size_t)NTOK * D_MODEL);
    float* xz   = alloc((size_t)NTOK * XZ_LD);
    float* xc   = alloc((size_t)NTOK * D_INNER);
    float* proj = alloc((size_t)NTOK * PROJ_LD);
    float* dt   = alloc((size_t)NTOK * D_INNER);
    float* y    = alloc((size_t)NTOK * D_INNER);

    embed_gather<<<NTOK, 192, 0, stream>>>(full_ids, embed, h);

    for (int l = 0; l < N_LAYERS; l++) {
        const float* inw  = in_w  + (size_t)l * 2 * D_INNER * D_MODEL;
        const float* cw   = conv_w + (size_t)l * D_INNER * CONV_K;
        const float* cb   = conv_b + (size_t)l * D_INNER;
        const float* xpw  = xp_w  + (size_t)l * PROJ_LD * D_INNER;
        const float* dtw  = dtp_w + (size_t)l * D_INNER * DT_RANK;
        const float* dtb  = dtp_b + (size_t)l * D_INNER;
        const float* Al   = A_log + (size_t)l * D_INNER * D_STATE;
        const float* Dl   = Dp    + (size_t)l * D_INNER;
        const float* ow   = out_w + (size_t)l * D_MODEL * D_INNER;

        rmsnorm_k<<<NTOK, 256, 0, stream>>>(h, norm_w + (size_t)l * D_MODEL, hn, D_MODEL);
        // xz = hn @ in_w^T   (512 x 3072, K=768)
        gemm_bt<<<dim3(2 * D_INNER / BN, NTOK / BM), 256, 0, stream>>>(
            hn, D_MODEL, inw, D_MODEL, xz, XZ_LD, NTOK, 2 * D_INNER, D_MODEL, 0, nullptr, nullptr);
        conv_silu<<<(NTOK * D_INNER + 255) / 256, 256, 0, stream>>>(xz, full_mask, cw, cb, xc);
        // proj = xc @ xp_w^T  (512 x 80, K=1536)
        gemm_bt<<<dim3((PROJ_LD + BN - 1) / BN, NTOK / BM), 256, 0, stream>>>(
            xc, D_INNER, xpw, D_INNER, proj, PROJ_LD, NTOK, PROJ_LD, D_INNER, 0, nullptr, nullptr);
        // dt = softplus(proj[:, :48] @ dtp_w^T + dtp_b)  (512 x 1536, K=48)
        gemm_bt<<<dim3(D_INNER / BN, NTOK / BM), 256, 0, stream>>>(
            proj, PROJ_LD, dtw, DT_RANK, dt, D_INNER, NTOK, D_INNER, DT_RANK, 1, dtb, nullptr);
        scan_k<<<(BATCH * D_INNER + 255) / 256, 256, 0, stream>>>(xz, xc, proj, dt, Al, Dl, y);
        // h = h + y @ out_w^T  (512 x 768, K=1536)
        gemm_bt<<<dim3(D_MODEL / BN, NTOK / BM), 256, 0, stream>>>(
            y, D_INNER, ow, D_INNER, h, D_MODEL, NTOK, D_MODEL, D_INNER, 2, nullptr, h);
    }

    rmsnorm_k<<<NTOK, 256, 0, stream>>>(h, norm_f_w, hn, D_MODEL);
    // logits = hn @ embed^T  (512 x 50280, K=768)
    gemm_bt<<<dim3((VOCAB + BN - 1) / BN, NTOK / BM), 256, 0, stream>>>(
        hn, D_MODEL, embed, D_MODEL, out, VOCAB, NTOK, VOCAB, D_MODEL, 0, nullptr, nullptr);
}

// Round 2
// 4263.411 us; speedup vs baseline: 1.9444x; 1.9444x over previous
//
#include <hip/hip_runtime.h>
#include <cmath>

#define N_LAYERS 24
#define D_MODEL 768
#define D_INNER 1536
#define D_STATE 16
#define DT_RANK 48
#define CONV_K 4
#define VOCAB 50280
#define SEQ 8
#define BATCH 64
#define NTOK (BATCH*SEQ)     /* 512 */
#define EPS 1e-5f
#define XZ_LD (2*D_INNER)    /* 3072 */
#define PROJ_LD (DT_RANK + 2*D_STATE) /* 80 */

typedef __attribute__((ext_vector_type(8))) __bf16 bf16x8;
typedef __attribute__((ext_vector_type(4))) float f32x4;

// ---------------- embedding gather ----------------
__global__ void embed_gather(const int* __restrict__ ids, const float* __restrict__ embed,
                             float* __restrict__ h) {
    int row = blockIdx.x;                 // token 0..511
    int b = row / SEQ, t = row % SEQ;
    int id = ids[b * 64 + t];             // full_ids is (64,64), take [:, :SEQ]
    const float4* src = (const float4*)(embed + (size_t)id * D_MODEL);
    float4* dst = (float4*)(h + (size_t)row * D_MODEL);
    dst[threadIdx.x] = src[threadIdx.x];  // 192 threads * 4 = 768
}

// ---------------- rmsnorm ----------------
__global__ void rmsnorm_k(const float* __restrict__ x, const float* __restrict__ w,
                          float* __restrict__ out, int D) {
    int row = blockIdx.x;
    const float* xr = x + (size_t)row * D;
    float s = 0.f;
    for (int i = threadIdx.x; i < D; i += blockDim.x) { float v = xr[i]; s += v * v; }
    #pragma unroll
    for (int off = 32; off; off >>= 1) s += __shfl_down(s, off);
    __shared__ float red[8];
    int lane = threadIdx.x & 63, wid = threadIdx.x >> 6;
    if (lane == 0) red[wid] = s;
    __syncthreads();
    if (threadIdx.x == 0) {
        float tot = 0.f;
        for (int i = 0; i < (int)(blockDim.x >> 6); i++) tot += red[i];
        red[0] = rsqrtf(tot / (float)D + EPS);
    }
    __syncthreads();
    float r = red[0];
    for (int i = threadIdx.x; i < D; i += blockDim.x)
        out[(size_t)row * D + i] = xr[i] * r * w[i];
}

// ---------------- MFMA bf16 GEMM-BT: C[M,N] = A[M,K] @ B[N,K]^T ----------------
// A, B are fp32 in global; converted to bf16 during LDS staging.
// epi: 0 plain store, 1 softplus(acc+bias[n]), 2 C += acc (read-modify-write),
//      3 atomicAdd(&C, acc)  (for split-K; C must hold the base value, e.g. residual)
// Requires M % 64 == 0; N guarded; K arbitrary (zero-padded per 8-chunk);
// lda/ldb multiples of 8 floats for the fast path alignment (all our LDs are).
#define LDSW 40   /* bf16 elems per LDS row: 32 data + 8 pad = 80 B (2-way max conflict) */
__global__ __launch_bounds__(256) void mgemm(
    const float* __restrict__ A, int lda,
    const float* __restrict__ B, int ldb,
    float* __restrict__ C, int ldc,
    int M, int N, int K, int KC,
    int epi, const float* __restrict__ bias)
{
    __shared__ __align__(16) __bf16 As[64 * LDSW];
    __shared__ __align__(16) __bf16 Bs[64 * LDSW];
    int tid = threadIdx.x;
    int m0 = blockIdx.y * 64, n0 = blockIdx.x * 64;
    int kstart = blockIdx.z * KC;
    int kend = kstart + KC; if (kend > K) kend = K;
    int wave = tid >> 6, lane = tid & 63;
    int l15 = lane & 15, quad = lane >> 4;
    int srow = tid >> 2;          // staging row 0..63
    int skq  = (tid & 3) * 8;     // staging k-chunk (8 floats)

    const float* Arow = A + (size_t)(m0 + srow) * lda;
    int brow = n0 + srow;
    const float* Brow = B + (size_t)brow * ldb;
    bool bvalid = brow < N;

    f32x4 acc[4];
    #pragma unroll
    for (int j = 0; j < 4; j++) acc[j] = (f32x4){0.f, 0.f, 0.f, 0.f};

    for (int k0 = kstart; k0 < kend; k0 += 32) {
        int kk = k0 + skq;
        // ---- stage A ----
        __bf16* ad = &As[srow * LDSW + skq];
        if (kk + 8 <= K) {
            float4 a0 = *(const float4*)(Arow + kk);
            float4 a1 = *(const float4*)(Arow + kk + 4);
            ad[0] = (__bf16)a0.x; ad[1] = (__bf16)a0.y; ad[2] = (__bf16)a0.z; ad[3] = (__bf16)a0.w;
            ad[4] = (__bf16)a1.x; ad[5] = (__bf16)a1.y; ad[6] = (__bf16)a1.z; ad[7] = (__bf16)a1.w;
        } else {
            #pragma unroll
            for (int e = 0; e < 8; e++) ad[e] = (kk + e < K) ? (__bf16)Arow[kk + e] : (__bf16)0.f;
        }
        // ---- stage B ----
        __bf16* bd = &Bs[srow * LDSW + skq];
        if (bvalid && kk + 8 <= K) {
            float4 b0 = *(const float4*)(Brow + kk);
            float4 b1 = *(const float4*)(Brow + kk + 4);
            bd[0] = (__bf16)b0.x; bd[1] = (__bf16)b0.y; bd[2] = (__bf16)b0.z; bd[3] = (__bf16)b0.w;
            bd[4] = (__bf16)b1.x; bd[5] = (__bf16)b1.y; bd[6] = (__bf16)b1.z; bd[7] = (__bf16)b1.w;
        } else {
            #pragma unroll
            for (int e = 0; e < 8; e++) bd[e] = (bvalid && kk + e < K) ? (__bf16)Brow[kk + e] : (__bf16)0.f;
        }
        __syncthreads();
        // ---- MFMA: wave handles rows [wave*16, wave*16+16), all 64 cols ----
        bf16x8 af = *(bf16x8*)&As[(wave * 16 + l15) * LDSW + quad * 8];
        #pragma unroll
        for (int j = 0; j < 4; j++) {
            bf16x8 bf = *(bf16x8*)&Bs[(j * 16 + l15) * LDSW + quad * 8];
            acc[j] = __builtin_amdgcn_mfma_f32_16x16x32_bf16(af, bf, acc[j], 0, 0, 0);
        }
        __syncthreads();
    }

    // ---- epilogue: C/D layout col=lane&15, row=quad*4+reg ----
    #pragma unroll
    for (int j = 0; j < 4; j++) {
        int n = n0 + j * 16 + l15;
        if (n >= N) continue;
        #pragma unroll
        for (int r = 0; r < 4; r++) {
            int m = m0 + wave * 16 + quad * 4 + r;
            float v = acc[j][r];
            size_t ci = (size_t)m * ldc + n;
            if (epi == 1) {
                v += bias[n];
                v = (v > 20.f) ? v : log1pf(expf(v));
                C[ci] = v;
            } else if (epi == 2) {
                C[ci] = C[ci] + v;
            } else if (epi == 3) {
                atomicAdd(&C[ci], v);
            } else {
                C[ci] = v;
            }
        }
    }
}

// ---------------- causal depthwise conv + bias + silu + mask ----------------
__global__ void conv_silu(const float* __restrict__ xz, const int* __restrict__ mask,
                          const float* __restrict__ cw, const float* __restrict__ cb,
                          float* __restrict__ xo)
{
    int idx = blockIdx.x * blockDim.x + threadIdx.x;
    if (idx >= NTOK * D_INNER) return;
    int d = idx % D_INNER;
    int row = idx / D_INNER;        // b*SEQ + t
    int t = row % SEQ, b = row / SEQ;
    float acc = cb[d];
    #pragma unroll
    for (int k = 0; k < CONV_K; k++) {
        int tt = t - (CONV_K - 1) + k;
        if (tt >= 0) {
            float xv = xz[(size_t)(b * SEQ + tt) * XZ_LD + d];
            float mf = (float)mask[b * 64 + tt];
            acc += xv * mf * cw[d * CONV_K + k];
        }
    }
    float mf = (float)mask[b * 64 + t];
    float sv = acc / (1.f + expf(-acc));   // silu
    xo[(size_t)row * D_INNER + d] = sv * mf;
}

// ---------------- selective scan + D-skip + z-gate ----------------
__global__ void scan_k(const float* __restrict__ xz, const float* __restrict__ xc,
                       const float* __restrict__ proj, const float* __restrict__ dt,
                       const float* __restrict__ A_log, const float* __restrict__ Dp,
                       float* __restrict__ y)
{
    int idx = blockIdx.x * blockDim.x + threadIdx.x;
    if (idx >= BATCH * D_INNER) return;
    int d = idx % D_INNER;
    int b = idx / D_INNER;
    float A[D_STATE];
    #pragma unroll
    for (int n = 0; n < D_STATE; n++) A[n] = -expf(A_log[d * D_STATE + n]);
    float Dv = Dp[d];
    float h[D_STATE];
    #pragma unroll
    for (int n = 0; n < D_STATE; n++) h[n] = 0.f;
    for (int t = 0; t < SEQ; t++) {
        int row = b * SEQ + t;
        float dtv = dt[(size_t)row * D_INNER + d];
        float xv = xc[(size_t)row * D_INNER + d];
        float yv = 0.f;
        #pragma unroll
        for (int n = 0; n < D_STATE; n++) {
            float dA = expf(dtv * A[n]);
            float Bv = proj[(size_t)row * PROJ_LD + DT_RANK + n];
            float Cv = proj[(size_t)row * PROJ_LD + DT_RANK + D_STATE + n];
            h[n] = dA * h[n] + dtv * Bv * xv;
            yv += h[n] * Cv;
        }
        yv += xv * Dv;
        float z = xz[(size_t)row * XZ_LD + D_INNER + d];
        yv *= z / (1.f + expf(-z));
        y[(size_t)row * D_INNER + d] = yv;
    }
}

extern "C" void kernel_launch(void* const* d_in, const int* in_sizes, int n_in,
                              void* d_out, int out_size, void* d_ws, size_t ws_size,
                              hipStream_t stream) {
    const int*   full_ids = (const int*)  d_in[0];
    const int*   full_mask= (const int*)  d_in[1];
    const float* embed    = (const float*)d_in[3];
    const float* norm_w   = (const float*)d_in[4];
    const float* in_w     = (const float*)d_in[5];
    const float* conv_w   = (const float*)d_in[6];
    const float* conv_b   = (const float*)d_in[7];
    const float* xp_w     = (const float*)d_in[8];
    const float* dtp_w    = (const float*)d_in[9];
    const float* dtp_b    = (const float*)d_in[10];
    const float* A_log    = (const float*)d_in[11];
    const float* Dp       = (const float*)d_in[12];
    const float* out_w    = (const float*)d_in[13];
    const float* norm_f_w = (const float*)d_in[14];
    float* out = (float*)d_out;

    // workspace carve-up (floats, 256B-aligned chunks)
    char* ws = (char*)d_ws;
    size_t off = 0;
    auto alloc = [&](size_t nfloats) {
        float* p = (float*)(ws + off);
        off += ((nfloats * 4 + 255) / 256) * 256;
        return p;
    };
    float* h    = alloc((size_t)NTOK * D_MODEL);
    float* hn   = alloc((size_t)NTOK * D_MODEL);
    float* xz   = alloc((size_t)NTOK * XZ_LD);
    float* xc   = alloc((size_t)NTOK * D_INNER);
    float* proj = alloc((size_t)NTOK * PROJ_LD);
    float* dt   = alloc((size_t)NTOK * D_INNER);
    float* y    = alloc((size_t)NTOK * D_INNER);

    embed_gather<<<NTOK, 192, 0, stream>>>(full_ids, embed, h);

    for (int l = 0; l < N_LAYERS; l++) {
        const float* inw  = in_w  + (size_t)l * 2 * D_INNER * D_MODEL;
        const float* cw   = conv_w + (size_t)l * D_INNER * CONV_K;
        const float* cb   = conv_b + (size_t)l * D_INNER;
        const float* xpw  = xp_w  + (size_t)l * PROJ_LD * D_INNER;
        const float* dtw  = dtp_w + (size_t)l * D_INNER * DT_RANK;
        const float* dtb  = dtp_b + (size_t)l * D_INNER;
        const float* Al   = A_log + (size_t)l * D_INNER * D_STATE;
        const float* Dl   = Dp    + (size_t)l * D_INNER;
        const float* ow   = out_w + (size_t)l * D_MODEL * D_INNER;

        rmsnorm_k<<<NTOK, 256, 0, stream>>>(h, norm_w + (size_t)l * D_MODEL, hn, D_MODEL);
        // xz = hn @ in_w^T   (512 x 3072, K=768)
        mgemm<<<dim3(2 * D_INNER / 64, NTOK / 64, 1), 256, 0, stream>>>(
            hn, D_MODEL, inw, D_MODEL, xz, XZ_LD, NTOK, 2 * D_INNER, D_MODEL, D_MODEL, 0, nullptr);
        conv_silu<<<(NTOK * D_INNER + 255) / 256, 256, 0, stream>>>(xz, full_mask, cw, cb, xc);
        // proj = xc @ xp_w^T  (512 x 80, K=1536)
        mgemm<<<dim3((PROJ_LD + 63) / 64, NTOK / 64, 1), 256, 0, stream>>>(
            xc, D_INNER, xpw, D_INNER, proj, PROJ_LD, NTOK, PROJ_LD, D_INNER, D_INNER, 0, nullptr);
        // dt = softplus(proj[:, :48] @ dtp_w^T + dtp_b)  (512 x 1536, K=48)
        mgemm<<<dim3(D_INNER / 64, NTOK / 64, 1), 256, 0, stream>>>(
            proj, PROJ_LD, dtw, DT_RANK, dt, D_INNER, NTOK, D_INNER, DT_RANK, DT_RANK, 1, dtb);
        scan_k<<<(BATCH * D_INNER + 255) / 256, 256, 0, stream>>>(xz, xc, proj, dt, Al, Dl, y);
        // h += y @ out_w^T  (512 x 768, K=1536), split-K z=4, atomicAdd into residual h
        mgemm<<<dim3(D_MODEL / 64, NTOK / 64, 4), 256, 0, stream>>>(
            y, D_INNER, ow, D_INNER, h, D_MODEL, NTOK, D_MODEL, D_INNER, 384, 3, nullptr);
    }

    rmsnorm_k<<<NTOK, 256, 0, stream>>>(h, norm_f_w, hn, D_MODEL);
    // logits = hn @ embed^T  (512 x 50280, K=768)
    mgemm<<<dim3((VOCAB + 63) / 64, NTOK / 64, 1), 256, 0, stream>>>(
        hn, D_MODEL, embed, D_MODEL, out, VOCAB, NTOK, VOCAB, D_MODEL, D_MODEL, 0, nullptr);
}